// Round 2
// baseline (229.792 us; speedup 1.0000x reference)
//
#include <hip/hip_runtime.h>
#include <hip/hip_bf16.h>
#include <cstdint>

#define RST 16777216  // 4096*4096 floats per rating class

// ---------------------------------------------------------------------------
// K0: zero du (2048 ints) + 3 scalars (loss_sum, acc_cnt, n_obs)
// ---------------------------------------------------------------------------
__global__ __launch_bounds__(256) void k_init(int* __restrict__ du, int* __restrict__ scalars){
  int tid = threadIdx.x;
#pragma unroll
  for (int k = 0; k < 8; k++) du[tid + k * 256] = 0;
  if (tid < 3) scalars[tid] = 0;
}

// ---------------------------------------------------------------------------
// K1: label extraction + di row-counts + n_obs. One block per batch-row i.
// Stage the 16KB rating row (per class) in LDS coalesced, gather at v[j].
// L[i,j] in {0..4}, 5 = unrated.
// ---------------------------------------------------------------------------
__global__ __launch_bounds__(256) void k_labels(const int* __restrict__ u, const int* __restrict__ v,
                                                const float* __restrict__ ratings, unsigned char* __restrict__ L,
                                                int* __restrict__ di, int* __restrict__ n_obs){
  __shared__ float row[4096];
  __shared__ int wsum[4];
  int i = blockIdx.x;
  int tid = threadIdx.x;
  int U = u[i];
  int j0 = tid * 8;
  int vj[8];
#pragma unroll
  for (int k = 0; k < 8; k++) vj[k] = v[j0 + k];
  int lab[8];
#pragma unroll
  for (int k = 0; k < 8; k++) lab[k] = 5;
  const float* rbase = ratings + (size_t)U * 4096;
  for (int c = 0; c < 5; c++){
    const float4* src = (const float4*)(rbase + (size_t)c * RST);
#pragma unroll
    for (int k = 0; k < 4; k++) ((float4*)row)[tid + k*256] = src[tid + k*256];
    __syncthreads();
#pragma unroll
    for (int k = 0; k < 8; k++) if (row[vj[k]] > 0.5f) lab[k] = c;
    __syncthreads();
  }
  unsigned int lo = 0, hi = 0;
  int cnt = 0;
#pragma unroll
  for (int k = 0; k < 4; k++){
    lo |= ((unsigned)lab[k]) << (8*k); hi |= ((unsigned)lab[k+4]) << (8*k);
    cnt += (lab[k] != 5); cnt += (lab[k+4] != 5);
  }
  *(uint2*)(L + (size_t)i * 2048 + j0) = make_uint2(lo, hi);
#pragma unroll
  for (int o = 32; o > 0; o >>= 1) cnt += __shfl_down(cnt, o);
  int wid = tid >> 6, lane = tid & 63;
  if (lane == 0) wsum[wid] = cnt;
  __syncthreads();
  if (tid == 0){
    int tot = wsum[0] + wsum[1] + wsum[2] + wsum[3];
    di[i] = tot;
    atomicAdd(n_obs, tot);
  }
}

// ---------------------------------------------------------------------------
// K2: byte transpose L -> LT (64x64 tiles via LDS) + du column counts
// ---------------------------------------------------------------------------
__global__ __launch_bounds__(256) void k_transpose(const unsigned char* __restrict__ L, unsigned char* __restrict__ LT,
                                                   int* __restrict__ du){
  __shared__ unsigned char tile[64][64];
  __shared__ int dpart[64][4];
  int i0 = blockIdx.y * 64, j0 = blockIdx.x * 64;
  int tid = threadIdx.x;
  int r = tid >> 2, cq = tid & 3;
  uint4 d = *(const uint4*)(L + (size_t)(i0 + r) * 2048 + j0 + cq * 16);
  *(uint4*)&tile[r][cq * 16] = d;
  __syncthreads();
  unsigned char ob[16];
  int cnt = 0;
#pragma unroll
  for (int k = 0; k < 16; k++){ ob[k] = tile[cq * 16 + k][r]; cnt += (ob[k] != 5); }
  *(uint4*)(LT + (size_t)(j0 + r) * 2048 + i0 + cq * 16) = *(uint4*)ob;
  dpart[r][cq] = cnt;
  __syncthreads();
  if (tid < 64) atomicAdd(&du[j0 + tid], dpart[tid][0] + dpart[tid][1] + dpart[tid][2] + dpart[tid][3]);
}

// ---------------------------------------------------------------------------
// K4: support S[c][n][h] = x[n,:] . gc_w[c,:,h]   (n<2048: ue; else ve)
// ---------------------------------------------------------------------------
__global__ __launch_bounds__(256) void k_support(const int* __restrict__ u, const int* __restrict__ v,
    const float* __restrict__ u_emb, const float* __restrict__ v_emb, const float* __restrict__ gc_w,
    float* __restrict__ S){
  int c = blockIdx.y;
  int lane = threadIdx.x & 63;
  int wid = threadIdx.x >> 6;
  int n0 = blockIdx.x * 64 + wid * 16;
  float w[64];
#pragma unroll
  for (int d = 0; d < 64; d++) w[d] = gc_w[c * 4096 + d * 64 + lane];
  for (int k = 0; k < 16; k++){
    int n = n0 + k;
    int idx = (n < 2048) ? u[n] : v[n - 2048];
    const float* xr = (n < 2048) ? (u_emb + (size_t)idx * 64) : (v_emb + (size_t)idx * 64);
    float xv = xr[lane];
    float acc = 0.f;
#pragma unroll
    for (int d = 0; d < 64; d++) acc += __shfl(xv, d) * w[d];
    S[((size_t)c * 4096 + n) * 64 + lane] = acc;
  }
}

// ---------------------------------------------------------------------------
// K5: sparse aggregate. Row r<2048: scan L row r, gather sv. Row r>=2048:
// scan LT row, gather su. 4 waves split the 2048-entry scan. Wave-uniform
// fast-skip when a 16-entry group is fully unrated (~18% of groups).
// ---------------------------------------------------------------------------
__global__ __launch_bounds__(256) void k_agg(const unsigned char* __restrict__ L, const unsigned char* __restrict__ LT,
    const float* __restrict__ S, float* __restrict__ aggsum){
  int r = blockIdx.x;
  int wid = threadIdx.x >> 6, lane = threadIdx.x & 63;
  bool uside = (r < 2048);
  const unsigned char* rowp = uside ? (L + (size_t)r * 2048) : (LT + (size_t)(r - 2048) * 2048);
  const float* Sop = S + (uside ? 131072 : 0) + lane;
  float acc = 0.f;
  const uint4* rp = (const uint4*)rowp;
  for (int it = 0; it < 32; it++){
    uint4 dd = rp[wid * 32 + it];
    if (dd.x == 0x05050505u && dd.y == 0x05050505u && dd.z == 0x05050505u && dd.w == 0x05050505u) continue;
    int jb = wid * 512 + it * 16;
#define PROCW(word, jo) { unsigned int w_ = (word); \
    int c0 = w_ & 255, c1 = (w_ >> 8) & 255, c2 = (w_ >> 16) & 255, c3 = (w_ >> 24); \
    if (c0 != 5) acc += Sop[(size_t)c0 * 262144 + (size_t)(jb + (jo) + 0) * 64]; \
    if (c1 != 5) acc += Sop[(size_t)c1 * 262144 + (size_t)(jb + (jo) + 1) * 64]; \
    if (c2 != 5) acc += Sop[(size_t)c2 * 262144 + (size_t)(jb + (jo) + 2) * 64]; \
    if (c3 != 5) acc += Sop[(size_t)c3 * 262144 + (size_t)(jb + (jo) + 3) * 64]; }
    PROCW(dd.x, 0) PROCW(dd.y, 4) PROCW(dd.z, 8) PROCW(dd.w, 12)
#undef PROCW
  }
  __shared__ float red[4][64];
  red[wid][lane] = acc;
  __syncthreads();
  if (wid == 0) aggsum[(size_t)r * 64 + lane] = red[0][lane] + red[1][lane] + red[2][lane] + red[3][lane];
}

// ---------------------------------------------------------------------------
// K6: z = relu(inv_count * aggsum + sum_c gc_b); hidden = sigmoid(z @ dense_w + dense_b)
// Reference quirk replicated: rows <2048 (users) use du (item/column counts),
// rows >=2048 (items) use di (user/row counts).
// ---------------------------------------------------------------------------
__global__ __launch_bounds__(256) void k_hidden(const float* __restrict__ aggsum, const int* __restrict__ du, const int* __restrict__ di,
    const float* __restrict__ gc_b, const float* __restrict__ dense_w, const float* __restrict__ dense_b,
    float* __restrict__ hidden){
  int wid = threadIdx.x >> 6, lane = threadIdx.x & 63;
  int r = blockIdx.x * 4 + wid;
  float a = aggsum[(size_t)r * 64 + lane];
  int cnt = (r < 2048) ? du[r] : di[r - 2048];
  float inv = (cnt > 0) ? (1.0f / (float)cnt) : 0.0f;
  float bsum = 0.f;
#pragma unroll
  for (int c = 0; c < 5; c++) bsum += gc_b[c * 64 + lane];
  float z = fmaxf(a * inv + bsum, 0.f);
  __shared__ float zb[4][64];
  zb[wid][lane] = z;
  __syncthreads();
  if (lane < 32){
    float s = dense_b[lane];
#pragma unroll
    for (int h = 0; h < 64; h++) s += zb[wid][h] * dense_w[h * 32 + lane];
    hidden[(size_t)r * 32 + lane] = 1.0f / (1.0f + __expf(-s));
  }
}

// ---------------------------------------------------------------------------
// K8: fused decoder-t + logits -> softmax -> m_hat + loss + accuracy.
// Tile: 16 i x 512 j per block, 2 j per thread. t-tile computed in-block
// (ts = hu_tile . dec_w, 2560 floats in LDS), hv rows in registers.
// ---------------------------------------------------------------------------
#define EPI(l, lab, outp) do{ \
  float mx = fmaxf(fmaxf(fmaxf(l[0], l[1]), fmaxf(l[2], l[3])), l[4]); \
  float e0 = __expf(l[0]-mx), e1 = __expf(l[1]-mx), e2 = __expf(l[2]-mx), e3 = __expf(l[3]-mx), e4 = __expf(l[4]-mx); \
  float ssum = e0 + e1 + e2 + e3 + e4; \
  *(outp) = (e1 + 2.f*e2 + 3.f*e3 + 4.f*e4) / ssum; \
  if ((lab) < 5){ \
    int pred = 0; float bm = l[0]; \
    if (l[1] > bm){ bm = l[1]; pred = 1; } \
    if (l[2] > bm){ bm = l[2]; pred = 2; } \
    if (l[3] > bm){ bm = l[3]; pred = 3; } \
    if (l[4] > bm){ bm = l[4]; pred = 4; } \
    float ll = (lab)==0 ? l[0] : ((lab)==1 ? l[1] : ((lab)==2 ? l[2] : ((lab)==3 ? l[3] : l[4]))); \
    lsum += __logf(ssum) + mx - ll; \
    acnt += (pred == (lab)); \
  } \
}while(0)

__global__ __launch_bounds__(256) void k_logits(const float* __restrict__ hidden, const float* __restrict__ dec_w,
    const unsigned char* __restrict__ L, float* __restrict__ mhat, float* __restrict__ loss_sum, int* __restrict__ acc_cnt){
  __shared__ float ts[2560];
  __shared__ float hu_s[512];
  int tid = threadIdx.x;
  int i0 = blockIdx.y * 16;
  int ja = blockIdx.x * 512 + tid;
  int jb = ja + 256;
  const float* hv = hidden + 2048 * 32;
  // stage hu tile (16 rows x 32)
  if (tid < 128) ((float4*)hu_s)[tid] = ((const float4*)(hidden + (size_t)i0 * 32))[tid];
  // load hv rows into registers (overlaps with hu staging)
  float hva[32], hvb[32];
#pragma unroll
  for (int q = 0; q < 8; q++){
    *(float4*)&hva[q * 4] = *(const float4*)(hv + (size_t)ja * 32 + q * 4);
    *(float4*)&hvb[q * 4] = *(const float4*)(hv + (size_t)jb * 32 + q * 4);
  }
  __syncthreads();
  // compute ts[c][ii][e] = hu[ii,:] . dec_w[c,:,e]  (2560 elements, 10/thread)
  for (int idx = tid; idx < 2560; idx += 256){
    int c = idx >> 9; int rem = idx & 511; int ii = rem >> 5; int e = rem & 31;
    const float* wc = dec_w + (size_t)c * 1024 + e;
    const float* hr = hu_s + ii * 32;
    float s = 0.f;
#pragma unroll
    for (int d = 0; d < 32; d++) s += hr[d] * wc[d * 32];
    ts[(c * 16 + ii) * 32 + e] = s;
  }
  __syncthreads();
  float lsum = 0.f; int acnt = 0;
  for (int ii = 0; ii < 16; ii++){
    int i = i0 + ii;
    float la[5], lb[5];
#pragma unroll
    for (int c = 0; c < 5; c++){
      const float4* tsr = (const float4*)(ts + (c * 16 + ii) * 32);
      float sa = 0.f, sb = 0.f;
#pragma unroll
      for (int q = 0; q < 8; q++){
        float4 tv = tsr[q];
        sa += tv.x * hva[q*4+0]; sa += tv.y * hva[q*4+1]; sa += tv.z * hva[q*4+2]; sa += tv.w * hva[q*4+3];
        sb += tv.x * hvb[q*4+0]; sb += tv.y * hvb[q*4+1]; sb += tv.z * hvb[q*4+2]; sb += tv.w * hvb[q*4+3];
      }
      la[c] = sa; lb[c] = sb;
    }
    int laba = L[(size_t)i * 2048 + ja];
    int labb = L[(size_t)i * 2048 + jb];
    EPI(la, laba, mhat + (size_t)i * 2048 + ja);
    EPI(lb, labb, mhat + (size_t)i * 2048 + jb);
  }
#pragma unroll
  for (int o = 32; o > 0; o >>= 1){ lsum += __shfl_down(lsum, o); acnt += __shfl_down(acnt, o); }
  __shared__ float wl[4]; __shared__ int wa[4];
  int wid = tid >> 6, lane = tid & 63;
  if (lane == 0){ wl[wid] = lsum; wa[wid] = acnt; }
  __syncthreads();
  if (tid == 0){ atomicAdd(loss_sum, wl[0] + wl[1] + wl[2] + wl[3]); atomicAdd(acc_cnt, wa[0] + wa[1] + wa[2] + wa[3]); }
}

// ---------------------------------------------------------------------------
// K9: finalize scalars
// ---------------------------------------------------------------------------
__global__ void k_final(const float* __restrict__ loss_sum, const int* __restrict__ acc_cnt,
                        const int* __restrict__ n_obs, float* __restrict__ out){
  float n = fmaxf((float)(*n_obs), 1.0f);
  out[0] = (*loss_sum) / n;
  out[1] = ((float)(*acc_cnt)) / n;
}

extern "C" void kernel_launch(void* const* d_in, const int* in_sizes, int n_in,
                              void* d_out, int out_size, void* d_ws, size_t ws_size,
                              hipStream_t stream){
  const int*   u       = (const int*)d_in[0];
  const int*   v       = (const int*)d_in[1];
  const float* ratings = (const float*)d_in[2];
  const float* u_emb   = (const float*)d_in[3];
  const float* v_emb   = (const float*)d_in[4];
  const float* gc_w    = (const float*)d_in[5];
  const float* gc_b    = (const float*)d_in[6];
  const float* dense_w = (const float*)d_in[7];
  const float* dense_b = (const float*)d_in[8];
  const float* dec_w   = (const float*)d_in[9];
  float* out = (float*)d_out;
  char* ws = (char*)d_ws;

  unsigned char* L   = (unsigned char*)(ws + 0);          // 4 MB
  unsigned char* LT  = (unsigned char*)(ws + 4194304);    // 4 MB
  float* S           = (float*)(ws + 8388608);            // 5 MB: [5][4096][64]
  float* aggsum      = (float*)(ws + 13631488);           // 1 MB: [4096][64]
  float* hidden      = (float*)(ws + 14680064);           // 512 KB: [4096][32]
  int*   du          = (int*)(ws + 15204352);             // 8 KB
  int*   di          = (int*)(ws + 15212544);             // 8 KB
  int*   scalars     = (int*)(ws + 15220736);             // loss_sum(f32), acc_cnt(i32), n_obs(i32)
  float* loss_sum    = (float*)(scalars + 0);
  int*   acc_cnt     = (int*)(scalars + 1);
  int*   n_obs       = (int*)(scalars + 2);

  k_init     <<<1, 256, 0, stream>>>(du, scalars);
  k_labels   <<<2048, 256, 0, stream>>>(u, v, ratings, L, di, n_obs);
  k_transpose<<<dim3(32, 32), 256, 0, stream>>>(L, LT, du);
  k_support  <<<dim3(64, 5), 256, 0, stream>>>(u, v, u_emb, v_emb, gc_w, S);
  k_agg      <<<4096, 256, 0, stream>>>(L, LT, S, aggsum);
  k_hidden   <<<1024, 256, 0, stream>>>(aggsum, du, di, gc_b, dense_w, dense_b, hidden);
  k_logits   <<<dim3(4, 128), 256, 0, stream>>>(hidden, dec_w, L, out, (float*)loss_sum, acc_cnt);
  k_final    <<<1, 1, 0, stream>>>(loss_sum, acc_cnt, n_obs, out + 4194304);
}

// Round 3
// 160.631 us; speedup vs baseline: 1.4306x; 1.4306x over previous
//
#include <hip/hip_runtime.h>
#include <hip/hip_bf16.h>
#include <cstdint>

#define RST 16777216  // 4096*4096 floats per rating class
typedef unsigned short u16;
typedef unsigned char u8;

// ---------------------------------------------------------------------------
// K1: label extraction + per-row compaction. One block per batch-row i.
// Stage the 16KB rating row (per class) in LDS coalesced, gather at v[j].
// Emits: L[i][j] (byte labels, 5=unrated), listU[i][*] = (j<<3|c) sorted by j,
// di[i] = count.
// ---------------------------------------------------------------------------
__global__ __launch_bounds__(256) void k_labels(const int* __restrict__ u, const int* __restrict__ v,
                                                const float* __restrict__ ratings, u8* __restrict__ L,
                                                u16* __restrict__ listU, int* __restrict__ di){
  __shared__ float row[4096];
  __shared__ int wbase[4];
  int i = blockIdx.x;
  int tid = threadIdx.x;
  int lane = tid & 63, wid = tid >> 6;
  int U = u[i];
  int j0 = tid * 8;
  int vj[8];
#pragma unroll
  for (int k = 0; k < 8; k++) vj[k] = v[j0 + k];
  int lab[8];
#pragma unroll
  for (int k = 0; k < 8; k++) lab[k] = 5;
  const float* rbase = ratings + (size_t)U * 4096;
  for (int c = 0; c < 5; c++){
    const float4* src = (const float4*)(rbase + (size_t)c * RST);
#pragma unroll
    for (int k = 0; k < 4; k++) ((float4*)row)[tid + k*256] = src[tid + k*256];
    __syncthreads();
#pragma unroll
    for (int k = 0; k < 8; k++) if (row[vj[k]] > 0.5f) lab[k] = c;
    __syncthreads();
  }
  // pack L bytes
  unsigned int lo = 0, hi = 0;
  int cnt = 0;
#pragma unroll
  for (int k = 0; k < 4; k++){
    lo |= ((unsigned)lab[k]) << (8*k); hi |= ((unsigned)lab[k+4]) << (8*k);
    cnt += (lab[k] != 5); cnt += (lab[k+4] != 5);
  }
  *(uint2*)(L + (size_t)i * 2048 + j0) = make_uint2(lo, hi);
  // wave-inclusive prefix sum of cnt
  int pre = cnt;
#pragma unroll
  for (int o = 1; o < 64; o <<= 1){ int t = __shfl_up(pre, o); if (lane >= o) pre += t; }
  if (lane == 63) wbase[wid] = pre;
  __syncthreads();
  int base = 0;
#pragma unroll
  for (int w = 0; w < 4; w++) base += (w < wid) ? wbase[w] : 0;
  int off = base + (pre - cnt);
  u16* dst = listU + (size_t)i * 512;
#pragma unroll
  for (int k = 0; k < 8; k++)
    if (lab[k] != 5) dst[off++] = (u16)(((j0 + k) << 3) | lab[k]);
  if (tid == 0) di[i] = wbase[0] + wbase[1] + wbase[2] + wbase[3];
}

// ---------------------------------------------------------------------------
// K2: byte transpose L -> LT (64x64 tiles via LDS)
// ---------------------------------------------------------------------------
__global__ __launch_bounds__(256) void k_transpose(const u8* __restrict__ L, u8* __restrict__ LT){
  __shared__ u8 tile[64][64];
  int i0 = blockIdx.y * 64, j0 = blockIdx.x * 64;
  int tid = threadIdx.x;
  int r = tid >> 2, cq = tid & 3;
  uint4 d = *(const uint4*)(L + (size_t)(i0 + r) * 2048 + j0 + cq * 16);
  *(uint4*)&tile[r][cq * 16] = d;
  __syncthreads();
  u8 ob[16];
#pragma unroll
  for (int k = 0; k < 16; k++) ob[k] = tile[cq * 16 + k][r];
  *(uint4*)(LT + (size_t)(j0 + r) * 2048 + i0 + cq * 16) = *(uint4*)ob;
}

// ---------------------------------------------------------------------------
// K3: compact LT rows -> listV[j][*] = (i<<3|c), du[j] = count.
// ---------------------------------------------------------------------------
__global__ __launch_bounds__(256) void k_compactV(const u8* __restrict__ LT, u16* __restrict__ listV,
                                                  int* __restrict__ du){
  __shared__ int wbase[4];
  int j = blockIdx.x;
  int tid = threadIdx.x;
  int lane = tid & 63, wid = tid >> 6;
  uint2 d = ((const uint2*)(LT + (size_t)j * 2048))[tid];
  int lab[8];
#pragma unroll
  for (int k = 0; k < 4; k++){ lab[k] = (d.x >> (8*k)) & 255; lab[k+4] = (d.y >> (8*k)) & 255; }
  int cnt = 0;
#pragma unroll
  for (int k = 0; k < 8; k++) cnt += (lab[k] != 5);
  int pre = cnt;
#pragma unroll
  for (int o = 1; o < 64; o <<= 1){ int t = __shfl_up(pre, o); if (lane >= o) pre += t; }
  if (lane == 63) wbase[wid] = pre;
  __syncthreads();
  int base = 0;
#pragma unroll
  for (int w = 0; w < 4; w++) base += (w < wid) ? wbase[w] : 0;
  int off = base + (pre - cnt);
  int i0 = tid * 8;
  u16* dst = listV + (size_t)j * 512;
#pragma unroll
  for (int k = 0; k < 8; k++)
    if (lab[k] != 5) dst[off++] = (u16)(((i0 + k) << 3) | lab[k]);
  if (tid == 0) du[j] = wbase[0] + wbase[1] + wbase[2] + wbase[3];
}

// ---------------------------------------------------------------------------
// K4: support S[c][n][h] = x[n,:] . gc_w[c,:,h]   (n<2048: ue; else ve)
// ---------------------------------------------------------------------------
__global__ __launch_bounds__(256) void k_support(const int* __restrict__ u, const int* __restrict__ v,
    const float* __restrict__ u_emb, const float* __restrict__ v_emb, const float* __restrict__ gc_w,
    float* __restrict__ S){
  int c = blockIdx.y;
  int lane = threadIdx.x & 63;
  int wid = threadIdx.x >> 6;
  int n0 = blockIdx.x * 64 + wid * 16;
  float w[64];
#pragma unroll
  for (int d = 0; d < 64; d++) w[d] = gc_w[c * 4096 + d * 64 + lane];
  for (int k = 0; k < 16; k++){
    int n = n0 + k;
    int idx = (n < 2048) ? u[n] : v[n - 2048];
    const float* xr = (n < 2048) ? (u_emb + (size_t)idx * 64) : (v_emb + (size_t)idx * 64);
    float xv = xr[lane];
    float acc = 0.f;
#pragma unroll
    for (int d = 0; d < 64; d++) acc += __shfl(xv, d) * w[d];
    S[((size_t)c * 4096 + n) * 64 + lane] = acc;
  }
}

// ---------------------------------------------------------------------------
// K5: sparse aggregate from compacted lists. Row r<2048: listU, gather sv.
// Row r>=2048: listV, gather su. List staged in LDS; 4 waves split entries;
// branch-free inner loop with 4 accumulators. lane = h.
// ---------------------------------------------------------------------------
__global__ __launch_bounds__(256) void k_agg(const u16* __restrict__ listU, const u16* __restrict__ listV,
    const int* __restrict__ di, const int* __restrict__ du,
    const float* __restrict__ S, float* __restrict__ aggsum){
  __shared__ u16 lst[512];
  __shared__ float red[4][64];
  int r = blockIdx.x;
  int wid = threadIdx.x >> 6, lane = threadIdx.x & 63;
  bool uside = (r < 2048);
  const u16* list = uside ? (listU + (size_t)r * 512) : (listV + (size_t)(r - 2048) * 512);
  int cnt = uside ? di[r] : du[r - 2048];
  const float* Sop = S + (uside ? 131072 : 0) + lane;
  if (threadIdx.x < 64) ((uint4*)lst)[threadIdx.x] = ((const uint4*)list)[threadIdx.x];
  __syncthreads();
  int e0 = (wid * cnt) >> 2, e1 = ((wid + 1) * cnt) >> 2;
  float a0 = 0.f, a1 = 0.f, a2 = 0.f, a3 = 0.f;
  int e = e0;
  for (; e + 4 <= e1; e += 4){
    int x0 = lst[e], x1 = lst[e+1], x2 = lst[e+2], x3 = lst[e+3];
    a0 += Sop[(size_t)(x0 & 7) * 262144 + (size_t)(x0 >> 3) * 64];
    a1 += Sop[(size_t)(x1 & 7) * 262144 + (size_t)(x1 >> 3) * 64];
    a2 += Sop[(size_t)(x2 & 7) * 262144 + (size_t)(x2 >> 3) * 64];
    a3 += Sop[(size_t)(x3 & 7) * 262144 + (size_t)(x3 >> 3) * 64];
  }
  for (; e < e1; e++){
    int x = lst[e];
    a0 += Sop[(size_t)(x & 7) * 262144 + (size_t)(x >> 3) * 64];
  }
  red[wid][lane] = (a0 + a1) + (a2 + a3);
  __syncthreads();
  if (wid == 0) aggsum[(size_t)r * 64 + lane] = red[0][lane] + red[1][lane] + red[2][lane] + red[3][lane];
}

// ---------------------------------------------------------------------------
// K6: z = relu(inv_count * aggsum + sum_c gc_b); hidden = sigmoid(z @ dense_w + dense_b)
// Reference quirk replicated: rows <2048 (users) use du (item/column counts),
// rows >=2048 (items) use di (user/row counts).
// ---------------------------------------------------------------------------
__global__ __launch_bounds__(256) void k_hidden(const float* __restrict__ aggsum, const int* __restrict__ du, const int* __restrict__ di,
    const float* __restrict__ gc_b, const float* __restrict__ dense_w, const float* __restrict__ dense_b,
    float* __restrict__ hidden){
  int wid = threadIdx.x >> 6, lane = threadIdx.x & 63;
  int r = blockIdx.x * 4 + wid;
  float a = aggsum[(size_t)r * 64 + lane];
  int cnt = (r < 2048) ? du[r] : di[r - 2048];
  float inv = (cnt > 0) ? (1.0f / (float)cnt) : 0.0f;
  float bsum = 0.f;
#pragma unroll
  for (int c = 0; c < 5; c++) bsum += gc_b[c * 64 + lane];
  float z = fmaxf(a * inv + bsum, 0.f);
  __shared__ float zb[4][64];
  zb[wid][lane] = z;
  __syncthreads();
  if (lane < 32){
    float s = dense_b[lane];
#pragma unroll
    for (int h = 0; h < 64; h++) s += zb[wid][h] * dense_w[h * 32 + lane];
    hidden[(size_t)r * 32 + lane] = 1.0f / (1.0f + __expf(-s));
  }
}

// ---------------------------------------------------------------------------
// K7: fused decoder-t + logits -> softmax -> m_hat + loss/accuracy partials.
// Tile: 16 i x 512 j per block, 2 j per thread. t-tile computed in-block.
// ---------------------------------------------------------------------------
#define EPI(l, lab, outp) do{ \
  float mx = fmaxf(fmaxf(fmaxf(l[0], l[1]), fmaxf(l[2], l[3])), l[4]); \
  float e0 = __expf(l[0]-mx), e1 = __expf(l[1]-mx), e2 = __expf(l[2]-mx), e3 = __expf(l[3]-mx), e4 = __expf(l[4]-mx); \
  float ssum = e0 + e1 + e2 + e3 + e4; \
  *(outp) = (e1 + 2.f*e2 + 3.f*e3 + 4.f*e4) / ssum; \
  if ((lab) < 5){ \
    int pred = 0; float bm = l[0]; \
    if (l[1] > bm){ bm = l[1]; pred = 1; } \
    if (l[2] > bm){ bm = l[2]; pred = 2; } \
    if (l[3] > bm){ bm = l[3]; pred = 3; } \
    if (l[4] > bm){ bm = l[4]; pred = 4; } \
    float ll = (lab)==0 ? l[0] : ((lab)==1 ? l[1] : ((lab)==2 ? l[2] : ((lab)==3 ? l[3] : l[4]))); \
    lsum += __logf(ssum) + mx - ll; \
    acnt += (pred == (lab)); \
  } \
}while(0)

__global__ __launch_bounds__(256) void k_logits(const float* __restrict__ hidden, const float* __restrict__ dec_w,
    const u8* __restrict__ L, float* __restrict__ mhat, float* __restrict__ lpart, int* __restrict__ apart){
  __shared__ float ts[2560];
  __shared__ float hu_s[512];
  int tid = threadIdx.x;
  int i0 = blockIdx.y * 16;
  int ja = blockIdx.x * 512 + tid;
  int jb = ja + 256;
  const float* hv = hidden + 2048 * 32;
  if (tid < 128) ((float4*)hu_s)[tid] = ((const float4*)(hidden + (size_t)i0 * 32))[tid];
  float hva[32], hvb[32];
#pragma unroll
  for (int q = 0; q < 8; q++){
    *(float4*)&hva[q * 4] = *(const float4*)(hv + (size_t)ja * 32 + q * 4);
    *(float4*)&hvb[q * 4] = *(const float4*)(hv + (size_t)jb * 32 + q * 4);
  }
  __syncthreads();
  for (int idx = tid; idx < 2560; idx += 256){
    int c = idx >> 9; int rem = idx & 511; int ii = rem >> 5; int e = rem & 31;
    const float* wc = dec_w + (size_t)c * 1024 + e;
    const float* hr = hu_s + ii * 32;
    float s = 0.f;
#pragma unroll
    for (int d = 0; d < 32; d++) s += hr[d] * wc[d * 32];
    ts[(c * 16 + ii) * 32 + e] = s;
  }
  __syncthreads();
  float lsum = 0.f; int acnt = 0;
  for (int ii = 0; ii < 16; ii++){
    int i = i0 + ii;
    float la[5], lb[5];
#pragma unroll
    for (int c = 0; c < 5; c++){
      const float4* tsr = (const float4*)(ts + (c * 16 + ii) * 32);
      float sa = 0.f, sb = 0.f;
#pragma unroll
      for (int q = 0; q < 8; q++){
        float4 tv = tsr[q];
        sa += tv.x * hva[q*4+0]; sa += tv.y * hva[q*4+1]; sa += tv.z * hva[q*4+2]; sa += tv.w * hva[q*4+3];
        sb += tv.x * hvb[q*4+0]; sb += tv.y * hvb[q*4+1]; sb += tv.z * hvb[q*4+2]; sb += tv.w * hvb[q*4+3];
      }
      la[c] = sa; lb[c] = sb;
    }
    int laba = L[(size_t)i * 2048 + ja];
    int labb = L[(size_t)i * 2048 + jb];
    EPI(la, laba, mhat + (size_t)i * 2048 + ja);
    EPI(lb, labb, mhat + (size_t)i * 2048 + jb);
  }
#pragma unroll
  for (int o = 32; o > 0; o >>= 1){ lsum += __shfl_down(lsum, o); acnt += __shfl_down(acnt, o); }
  __shared__ float wl[4]; __shared__ int wa[4];
  int wid = tid >> 6, lane = tid & 63;
  if (lane == 0){ wl[wid] = lsum; wa[wid] = acnt; }
  __syncthreads();
  if (tid == 0){
    int pb = blockIdx.y * 4 + blockIdx.x;
    lpart[pb] = wl[0] + wl[1] + wl[2] + wl[3];
    apart[pb] = wa[0] + wa[1] + wa[2] + wa[3];
  }
}

// ---------------------------------------------------------------------------
// K8: final reduce: loss = sum(lpart)/n_obs, acc = sum(apart)/n_obs, n_obs = sum(di)
// ---------------------------------------------------------------------------
__global__ __launch_bounds__(256) void k_final(const float* __restrict__ lpart, const int* __restrict__ apart,
                                               const int* __restrict__ di, float* __restrict__ out){
  __shared__ float lred[256];
  __shared__ int ared[256], nred[256];
  int tid = threadIdx.x;
  float ls = lpart[tid] + lpart[tid + 256];
  int as = apart[tid] + apart[tid + 256];
  int ns = 0;
#pragma unroll
  for (int k = 0; k < 8; k++) ns += di[tid + k * 256];
  lred[tid] = ls; ared[tid] = as; nred[tid] = ns;
  __syncthreads();
  for (int s = 128; s > 0; s >>= 1){
    if (tid < s){ lred[tid] += lred[tid + s]; ared[tid] += ared[tid + s]; nred[tid] += nred[tid + s]; }
    __syncthreads();
  }
  if (tid == 0){
    float n = fmaxf((float)nred[0], 1.0f);
    out[0] = lred[0] / n;
    out[1] = ((float)ared[0]) / n;
  }
}

extern "C" void kernel_launch(void* const* d_in, const int* in_sizes, int n_in,
                              void* d_out, int out_size, void* d_ws, size_t ws_size,
                              hipStream_t stream){
  const int*   u       = (const int*)d_in[0];
  const int*   v       = (const int*)d_in[1];
  const float* ratings = (const float*)d_in[2];
  const float* u_emb   = (const float*)d_in[3];
  const float* v_emb   = (const float*)d_in[4];
  const float* gc_w    = (const float*)d_in[5];
  const float* gc_b    = (const float*)d_in[6];
  const float* dense_w = (const float*)d_in[7];
  const float* dense_b = (const float*)d_in[8];
  const float* dec_w   = (const float*)d_in[9];
  float* out = (float*)d_out;
  char* ws = (char*)d_ws;

  u8*    L       = (u8*)(ws + 0);                 // 4 MB
  u8*    LT      = (u8*)(ws + 4194304);           // 4 MB
  float* S       = (float*)(ws + 8388608);        // 5 MB: [5][4096][64]
  float* aggsum  = (float*)(ws + 13631488);       // 1 MB: [4096][64]
  float* hidden  = (float*)(ws + 14680064);       // 512 KB: [4096][32]
  u16*   listU   = (u16*)(ws + 15204352);         // 2 MB: [2048][512]
  u16*   listV   = (u16*)(ws + 17301504);         // 2 MB: [2048][512]
  int*   di      = (int*)(ws + 19398656);         // 8 KB
  int*   du      = (int*)(ws + 19406848);         // 8 KB
  float* lpart   = (float*)(ws + 19415040);       // 2 KB: [512]
  int*   apart   = (int*)(ws + 19417088);         // 2 KB: [512]

  k_labels   <<<2048, 256, 0, stream>>>(u, v, ratings, L, listU, di);
  k_transpose<<<dim3(32, 32), 256, 0, stream>>>(L, LT);
  k_compactV <<<2048, 256, 0, stream>>>(LT, listV, du);
  k_support  <<<dim3(64, 5), 256, 0, stream>>>(u, v, u_emb, v_emb, gc_w, S);
  k_agg      <<<4096, 256, 0, stream>>>(listU, listV, di, du, S, aggsum);
  k_hidden   <<<1024, 256, 0, stream>>>(aggsum, du, di, gc_b, dense_w, dense_b, hidden);
  k_logits   <<<dim3(4, 128), 256, 0, stream>>>(hidden, dec_w, L, out, lpart, apart);
  k_final    <<<1, 256, 0, stream>>>(lpart, apart, di, out + 4194304);
}